// Round 7
// baseline (419.874 us; speedup 1.0000x reference)
//
#include <hip/hip_runtime.h>
#include <stdint.h>

#define DN 128
#define NBITS 6          // 64 nodes per bucket
#define BNODES 64
#define HB 2048          // padded bucket count (pow2)
#define NSL 64           // edge slices for hist/scatter
#define NLOC 256         // buckets per XCD-chunk (HB/8); owner p = bucket & 7

__host__ __device__ static inline int divup(int a, int b){ return (a+b-1)/b; }

typedef __attribute__((ext_vector_type(8))) short bf16x8;
typedef __attribute__((ext_vector_type(4))) float floatx4;

__device__ __forceinline__ unsigned short f2bf(float f){
  unsigned int x = __float_as_uint(f);
  unsigned int r = x + 0x7fffu + ((x >> 16) & 1u);   // RNE
  return (unsigned short)(r >> 16);
}
__device__ __forceinline__ unsigned int pack2(unsigned short a, unsigned short b){
  return (unsigned int)a | ((unsigned int)b << 16);
}

// Slab layout: 8 slabs of 16 cols; slab q holds cols [16q,16q+16).
// addr(arr, node, col) = arr + (col>>4)*n*16 + node*16 + (col&15)   [ushort units]

// ---------------- bucket partition (atomic-free, XCD-local scatter) ----------------

__global__ __launch_bounds__(256)
void hist_pass(const int* __restrict__ dst, int* __restrict__ gHist, int E){
  __shared__ int h[NLOC];
  int p = blockIdx.x & 7, s = blockIdx.x >> 3;
  int t = threadIdx.x;
  h[t] = 0;
  __syncthreads();
  int n4 = E >> 2, per4 = divup(n4, NSL);
  int lo = s*per4, hi = min(lo+per4, n4);
  const int4* dst4 = (const int4*)dst;
  for (int i = lo + t; i < hi; i += 256){
    int4 d4 = dst4[i];
    int dd[4] = {d4.x, d4.y, d4.z, d4.w};
    #pragma unroll
    for (int j=0;j<4;j++){
      int b = dd[j] >> NBITS;
      if ((b & 7) == p) atomicAdd(&h[b>>3], 1);
    }
  }
  if (s == NSL-1){  // global tail E%4
    for (int e = (n4<<2) + t; e < E; e += 256){
      int b = dst[e] >> NBITS;
      if ((b & 7) == p) atomicAdd(&h[b>>3], 1);
    }
  }
  __syncthreads();
  gHist[blockIdx.x*NLOC + t] = h[t];
}

__global__ __launch_bounds__(256)
void scan_offsets(const int* __restrict__ gHist, int* __restrict__ blockOffset,
                  int* __restrict__ bucketTotal){
  int b = blockIdx.x*4 + (threadIdx.x >> 6);     // bucket
  int k = threadIdx.x & 63;                      // slice
  int p = b & 7, lb = b >> 3;
  int idx = (k*8 + p)*NLOC + lb;
  int v = gHist[idx];
  int sft = v;
  #pragma unroll
  for (int off=1; off<64; off<<=1){
    int u = __shfl_up(sft, off, 64);
    if (k >= off) sft += u;
  }
  blockOffset[idx] = sft - v;                    // exclusive over slices
  if (k == 63) bucketTotal[b] = sft;
}

__global__ __launch_bounds__(256)
void bucket_base(const int* __restrict__ bucketTotal, int* __restrict__ bucketBase){
  __shared__ int s[256];
  int t = threadIdx.x;
  int v[8]; int sum = 0;
  #pragma unroll
  for (int j=0;j<8;j++){ v[j] = bucketTotal[t*8+j]; sum += v[j]; }
  s[t] = sum; __syncthreads();
  for (int off=1; off<256; off<<=1){
    int y = (t>=off)? s[t-off] : 0;
    __syncthreads();
    s[t] += y;
    __syncthreads();
  }
  int excl = s[t] - sum;
  #pragma unroll
  for (int j=0;j<8;j++){ bucketBase[t*8+j] = excl; excl += v[j]; }
  if (t == 255) bucketBase[HB] = excl;           // = E
}

__global__ __launch_bounds__(256)
void scatter_pass(const int* __restrict__ src, const int* __restrict__ dst,
                  const int* __restrict__ bucketBase, const int* __restrict__ blockOffset,
                  unsigned int* __restrict__ packed, int E){
  __shared__ int cur[NLOC];
  int p = blockIdx.x & 7, s = blockIdx.x >> 3;
  int t = threadIdx.x;
  cur[t] = bucketBase[(t<<3)|p] + blockOffset[blockIdx.x*NLOC + t];
  __syncthreads();
  int n4 = E >> 2, per4 = divup(n4, NSL);
  int lo = s*per4, hi = min(lo+per4, n4);
  const int4* dst4 = (const int4*)dst;
  const int4* src4 = (const int4*)src;
  for (int i = lo + t; i < hi; i += 256){
    int4 d4 = dst4[i];
    int4 s4 = src4[i];
    int dd[4] = {d4.x, d4.y, d4.z, d4.w};
    int ss[4] = {s4.x, s4.y, s4.z, s4.w};
    #pragma unroll
    for (int j=0;j<4;j++){
      int d = dd[j], b = d >> NBITS;
      if ((b & 7) == p){
        int pos = atomicAdd(&cur[b>>3], 1);
        packed[pos] = (unsigned)ss[j] | ((unsigned)(d & (BNODES-1)) << 17);
      }
    }
  }
  if (s == NSL-1){
    for (int e = (n4<<2) + t; e < E; e += 256){
      int d = dst[e], b = d >> NBITS;
      if ((b & 7) == p){
        int pos = atomicAdd(&cur[b>>3], 1);
        packed[pos] = (unsigned)src[e] | ((unsigned)(d & (BNODES-1)) << 17);
      }
    }
  }
}

__global__ __launch_bounds__(256)
void node_sort(const int* __restrict__ bucketBase, const unsigned int* __restrict__ packed,
               int* __restrict__ csr_src, int* __restrict__ nodeOff, int n){
  __shared__ int cnts[BNODES], offs[BNODES+1], cursor[BNODES];
  int b = blockIdx.x, t = threadIdx.x;
  int beg = bucketBase[b], end = bucketBase[b+1], cnt = end - beg;
  if (t < BNODES) cnts[t] = 0;
  __syncthreads();
  for (int i=t; i<cnt; i+=256) atomicAdd(&cnts[(packed[beg+i]>>17)&63], 1);
  __syncthreads();
  if (t < BNODES){       // wave 0: shfl prefix over 64 nodes
    int v = cnts[t], sft = v;
    #pragma unroll
    for (int off=1; off<64; off<<=1){
      int u = __shfl_up(sft, off, 64);
      if (t >= off) sft += u;
    }
    offs[t] = sft - v; cursor[t] = sft - v;
    if (t == 63) offs[BNODES] = sft;
  }
  __syncthreads();
  for (int i=t; i<cnt; i+=256){
    unsigned pk = packed[beg+i];
    int nd = (pk>>17)&63;
    int r = atomicAdd(&cursor[nd], 1);
    csr_src[beg + r] = (int)(pk & 0x1FFFFu);
  }
  if (t <= BNODES){
    int node = b*BNODES + t;
    if (node <= n) nodeOff[node] = beg + offs[t];   // node==n -> sentinel = E
  }
}

// ---------------- fp32 -> bf16 conversions (slab output for x) ----------------

__global__ __launch_bounds__(256)
void convert_x_kernel(const float* __restrict__ src, unsigned short* __restrict__ dst,
                      int count8, int n){
  int i = blockIdx.x*256 + threadIdx.x;
  if (i >= count8) return;
  const float4* s = (const float4*)src + (size_t)i*2;
  float4 a = s[0], b = s[1];
  uint4 o;
  o.x = pack2(f2bf(a.x), f2bf(a.y));
  o.y = pack2(f2bf(a.z), f2bf(a.w));
  o.z = pack2(f2bf(b.x), f2bf(b.y));
  o.w = pack2(f2bf(b.z), f2bf(b.w));
  int row = i >> 4, c8 = i & 15;                 // 8-col chunk index within row
  // slab q = c8>>1, offset = (c8&1)*8
  unsigned short* d = dst + (size_t)(c8>>1)*n*16 + (size_t)row*16 + (c8&1)*8;
  *(uint4*)d = o;
}

__global__ __launch_bounds__(256)
void convert_w_kernel(const float* __restrict__ w0, const float* __restrict__ w1,
                      const float* __restrict__ w2, const float* __restrict__ w3,
                      unsigned short* __restrict__ dst){
  int tid = blockIdx.x*256 + threadIdx.x;          // 0..8191
  if (tid >= 8192) return;
  int mat = tid >> 11, off = tid & 2047;
  const float* w = (mat==0)?w0:(mat==1)?w1:(mat==2)?w2:w3;
  const float4* s = (const float4*)w + (size_t)off*2;
  float4 a = s[0], b = s[1];
  uint4 o;
  o.x = pack2(f2bf(a.x), f2bf(a.y));
  o.y = pack2(f2bf(a.z), f2bf(a.w));
  o.z = pack2(f2bf(b.x), f2bf(b.y));
  o.w = pack2(f2bf(b.z), f2bf(b.w));
  ((uint4*)(dst + (size_t)mat*16384))[off] = o;
}

// ---------------- mean aggregation (column-slab, XCD-L2-resident gather) ----------------
// Block b: slab p = b&7 (pinned to XCD p by round-robin dispatch), slice s = b>>3.
// Thread pair per node: half = t&1 covers 8 cols (16 B). The gather working set
// is one slab (n*32 B = 3.2 MB) -> resident in that XCD's 4 MB L2.
__global__ __launch_bounds__(256)
void aggregate_slab(const unsigned short* __restrict__ xs, const int* __restrict__ nodeOff,
                    const int* __restrict__ csr_src, unsigned short* __restrict__ aggs, int n){
  int p = blockIdx.x & 7, s = blockIdx.x >> 3;
  int t = threadIdx.x;
  int pid = t >> 1, half = t & 1;
  const unsigned short* slab = xs + (size_t)p*n*16;
  unsigned short* oslab = aggs + (size_t)p*n*16;
  #define ACCUM(u) { unsigned int w;                                   \
      w=(u).x; acc[0]+=__uint_as_float(w<<16); acc[1]+=__uint_as_float(w&0xffff0000u); \
      w=(u).y; acc[2]+=__uint_as_float(w<<16); acc[3]+=__uint_as_float(w&0xffff0000u); \
      w=(u).z; acc[4]+=__uint_as_float(w<<16); acc[5]+=__uint_as_float(w&0xffff0000u); \
      w=(u).w; acc[6]+=__uint_as_float(w<<16); acc[7]+=__uint_as_float(w&0xffff0000u); }
  for (int g = s*128 + pid; g < n; g += NSL*128){
    int beg = nodeOff[g], end = nodeOff[g+1];
    float acc[8] = {0,0,0,0,0,0,0,0};
    int e = beg;
    for (; e+4 <= end; e += 4){
      int s0 = csr_src[e], s1 = csr_src[e+1], s2 = csr_src[e+2], s3 = csr_src[e+3];
      uint4 u0 = *(const uint4*)(slab + (size_t)s0*16 + half*8);
      uint4 u1 = *(const uint4*)(slab + (size_t)s1*16 + half*8);
      uint4 u2 = *(const uint4*)(slab + (size_t)s2*16 + half*8);
      uint4 u3 = *(const uint4*)(slab + (size_t)s3*16 + half*8);
      ACCUM(u0) ACCUM(u1) ACCUM(u2) ACCUM(u3)
    }
    for (; e < end; ++e){
      int s0 = csr_src[e];
      uint4 u0 = *(const uint4*)(slab + (size_t)s0*16 + half*8);
      ACCUM(u0)
    }
    float inv = 1.f / fmaxf((float)(end-beg), 1.f);
    uint4 o;
    o.x = pack2(f2bf(acc[0]*inv), f2bf(acc[1]*inv));
    o.y = pack2(f2bf(acc[2]*inv), f2bf(acc[3]*inv));
    o.z = pack2(f2bf(acc[4]*inv), f2bf(acc[5]*inv));
    o.w = pack2(f2bf(acc[6]*inv), f2bf(acc[7]*inv));
    *(uint4*)(oslab + (size_t)g*16 + half*8) = o;
  }
  #undef ACCUM
}

// ---------------- dual-GEMM via bf16 MFMA (slab-layout A), no LDS ----------------
__device__ __forceinline__ bf16x8 load_slabA(const unsigned short* base, int n, int row, int c){
  return *(const bf16x8*)(base + (size_t)(c>>4)*n*16 + (size_t)row*16 + (c&15));
}

template<bool RELU, bool OUT_BF16>
__global__ __launch_bounds__(256)
void gemm_mfma(const unsigned short* __restrict__ A1, const unsigned short* __restrict__ W1b,
               const unsigned short* __restrict__ A2, const unsigned short* __restrict__ W2b,
               const float* __restrict__ bias, void* __restrict__ out,
               int rt_total, int rt_per_block, int n)
{
  int wave = threadIdx.x >> 6;
  int lane = threadIdx.x & 63;
  int m = lane & 15, quad = lane >> 4;

  bf16x8 Bf[2][2][4];   // persistent B fragments: [ct2][mat][kc]
  {
    const unsigned short* Ws[2] = {W1b, W2b};
    #pragma unroll
    for (int c2=0;c2<2;c2++){
      int col = wave*32 + c2*16 + m;
      #pragma unroll
      for (int mat=0;mat<2;mat++){
        const unsigned short* wrow = Ws[mat] + (size_t)col*DN + quad*8;
        #pragma unroll
        for (int kc=0;kc<4;kc++)
          Bf[c2][mat][kc] = *(const bf16x8*)(wrow + kc*32);
      }
    }
  }
  float bv0 = bias[wave*32 + m];
  float bv1 = bias[wave*32 + 16 + m];

  int rt_begin = blockIdx.x * rt_per_block;
  int rt_end = rt_begin + rt_per_block; if (rt_end > rt_total) rt_end = rt_total;

  for (int rt = rt_begin; rt < rt_end; ++rt){
    int row0 = rt*16 + m;
    bf16x8 Af[2][4];
    #pragma unroll
    for (int kc=0;kc<4;kc++){
      int c = kc*32 + quad*8;
      Af[0][kc] = load_slabA(A1, n, row0, c);
      Af[1][kc] = load_slabA(A2, n, row0, c);
    }
    __syncthreads();   // drains loads; all waves past load phase before stores
    floatx4 acc0 = {0.f,0.f,0.f,0.f}, acc1 = {0.f,0.f,0.f,0.f};
    #pragma unroll
    for (int mat=0; mat<2; mat++)
      #pragma unroll
      for (int kc=0; kc<4; kc++){
        acc0 = __builtin_amdgcn_mfma_f32_16x16x32_bf16(Af[mat][kc], Bf[0][mat][kc], acc0, 0,0,0);
        acc1 = __builtin_amdgcn_mfma_f32_16x16x32_bf16(Af[mat][kc], Bf[1][mat][kc], acc1, 0,0,0);
      }
    #pragma unroll
    for (int r=0;r<4;r++){
      int row = rt*16 + quad*4 + r;
      float v0 = acc0[r] + bv0;
      float v1 = acc1[r] + bv1;
      if (RELU){ v0 = fmaxf(v0, 0.f); v1 = fmaxf(v1, 0.f); }
      if (OUT_BF16){
        // slab layout: col0 = wave*32+m -> slab 2*wave; col1 = +16 -> slab 2*wave+1
        unsigned short* o = (unsigned short*)out;
        o[(size_t)(2*wave  )*n*16 + (size_t)row*16 + m] = f2bf(v0);
        o[(size_t)(2*wave+1)*n*16 + (size_t)row*16 + m] = f2bf(v1);
      } else {
        float* o = (float*)out + (size_t)row*DN + wave*32 + m;
        o[0]  = v0;
        o[16] = v1;
      }
    }
  }
}

// ---------------- launch ----------------

extern "C" void kernel_launch(void* const* d_in, const int* in_sizes, int n_in,
                              void* d_out, int out_size, void* d_ws, size_t ws_size,
                              hipStream_t stream) {
  const float* x   = (const float*)d_in[0];
  const int*   ei  = (const int*)d_in[1];
  const float* Wl1 = (const float*)d_in[2];
  const float* bl1 = (const float*)d_in[3];
  const float* Wr1 = (const float*)d_in[4];
  const float* Wl2 = (const float*)d_in[5];
  const float* bl2 = (const float*)d_in[6];
  const float* Wr2 = (const float*)d_in[7];

  const int n = in_sizes[0] / DN;     // 100000
  const int E = in_sizes[1] / 2;      // 1600000
  const int* src = ei;
  const int* dst = ei + E;

  // workspace: gHist | blockOffset | totals | base | packed | csr_src | nodeOff | Wb | xb | aggb [| hb]
  char* ws = (char*)d_ws;
  char* ws_end = ws + ws_size;
  int* gHist       = (int*)ws;  ws += (size_t)NSL*8*NLOC*4;   // 512 KB
  int* blockOffset = (int*)ws;  ws += (size_t)NSL*8*NLOC*4;   // 512 KB
  int* bucketTotal = (int*)ws;  ws += (size_t)HB*4;
  int* bucketBase  = (int*)ws;  ws += (size_t)(HB+1)*4;
  ws = (char*)(((uintptr_t)ws + 255) & ~(uintptr_t)255);
  unsigned int* packed = (unsigned int*)ws; ws += (size_t)E*4; // 6.4 MB
  int* csr_src     = (int*)ws;  ws += (size_t)E*4;             // 6.4 MB
  int* nodeOff     = (int*)ws;  ws += (size_t)(n+1)*4;
  ws = (char*)(((uintptr_t)ws + 255) & ~(uintptr_t)255);
  unsigned short* Wb   = (unsigned short*)ws; ws += 4*16384*2;
  unsigned short* xb   = (unsigned short*)ws; ws += (size_t)n*DN*2;   // slab layout
  unsigned short* aggb = (unsigned short*)ws; ws += (size_t)n*DN*2;   // slab layout
  unsigned short* hb = xb;   // in-place fallback (gemm stages A before writing)
  if (ws + (size_t)n*DN*2 <= ws_end) { hb = (unsigned short*)ws; ws += (size_t)n*DN*2; }

  unsigned short* Wl1b = Wb;
  unsigned short* Wr1b = Wb + 16384;
  unsigned short* Wl2b = Wb + 2*16384;
  unsigned short* Wr2b = Wb + 3*16384;

  hist_pass   <<<NSL*8, 256,0,stream>>>(dst, gHist, E);
  scan_offsets<<<HB/4,  256,0,stream>>>(gHist, blockOffset, bucketTotal);
  bucket_base <<<1,     256,0,stream>>>(bucketTotal, bucketBase);
  scatter_pass<<<NSL*8, 256,0,stream>>>(src, dst, bucketBase, blockOffset, packed, E);
  node_sort   <<<HB,    256,0,stream>>>(bucketBase, packed, csr_src, nodeOff, n);

  convert_x_kernel<<<divup(n*DN/8,256),256,0,stream>>>(x, xb, n*DN/8, n);
  convert_w_kernel<<<32,256,0,stream>>>(Wl1, Wr1, Wl2, Wr2, Wb);

  const int rt_total = n / 16;                  // 6250
  const int rt_per_block = 5;
  const int gblocks = divup(rt_total, rt_per_block);

  // layer 1: h = relu(agg@Wl1^T + x@Wr1^T + b1), bf16 slab out
  aggregate_slab<<<NSL*8,256,0,stream>>>(xb, nodeOff, csr_src, aggb, n);
  gemm_mfma<true, true><<<gblocks,256,0,stream>>>(aggb, Wl1b, xb, Wr1b, bl1, hb, rt_total, rt_per_block, n);
  // layer 2: out = agg@Wl2^T + h@Wr2^T + b2, fp32 row out
  aggregate_slab<<<NSL*8,256,0,stream>>>(hb, nodeOff, csr_src, aggb, n);
  gemm_mfma<false,false><<<gblocks,256,0,stream>>>(aggb, Wl2b, hb, Wr2b, bl2, d_out, rt_total, rt_per_block, n);
}